// Round 6
// baseline (209.775 us; speedup 1.0000x reference)
//
#include <hip/hip_runtime.h>
#include <math.h>

#define BB 64
#define SS 512
#define HH 768
#define AA1 100
#define CC1 300

typedef __bf16 bf16x8 __attribute__((ext_vector_type(8)));
typedef float f32x4 __attribute__((ext_vector_type(4)));

// ---------------------------------------------------------------------------
// Prep: B image (chunk-major per 32-K tile, zero-pad j>=100)
//   w1i[((kt*4+q)*112 + j)*8 + e] = bf16(w1[(kt*32+q*8+e)*100 + j])
// ---------------------------------------------------------------------------
__global__ __launch_bounds__(256) void k_prep(const float* __restrict__ w1,
                                              __bf16* __restrict__ w1i) {
    int idx = blockIdx.x * 256 + threadIdx.x;   // 86016 = 336*256
    int j = idx % 112;
    int r = idx / 112;
    int e = r & 7, g = r >> 3;  // g = kt*4 + q
    int k = (g >> 2) * 32 + (g & 3) * 8 + e;
    float v = (j < AA1) ? w1[k * AA1 + j] : 0.f;
    w1i[((size_t)g * 112 + j) * 8 + e] = (__bf16)v;
}

// ---------------------------------------------------------------------------
// Kernel 1: token attention, bf16 MFMA 16x16x32, barrier-free / LDS-free.
// Grid 512 x 256: wave w owns 16 tokens (1 M-tile) x 7 N-tiles.
// Lane (q,ln): A row = tok0+w*16+ln, k = q*8+e; B = w1[q*8+e][n*16+ln].
// ---------------------------------------------------------------------------
__global__ __launch_bounds__(256) void k_token_att(
        const float* __restrict__ hs, const __bf16* __restrict__ w1i,
        const float* __restrict__ b1, const float* __restrict__ w2,
        const float* __restrict__ b2, float* __restrict__ token_att) {
    const int tid = threadIdx.x;
    const int tok0 = blockIdx.x * 64;
    const int w = tid >> 6, lane = tid & 63;
    const int q = lane >> 4, ln = lane & 15;
    const int trow = tok0 + w * 16 + ln;     // A-fragment row for this lane

    f32x4 acc[7];
#pragma unroll
    for (int n = 0; n < 7; n++) acc[n] = (f32x4){0.f, 0.f, 0.f, 0.f};

    const float* ga = hs + (size_t)trow * HH + q * 8;
    const __bf16* gb = w1i + (size_t)(q * 112 + ln) * 8;

#pragma unroll 4
    for (int kt = 0; kt < 24; kt++) {
        f32x4 a0 = *(const f32x4*)(ga + kt * 32);
        f32x4 a1 = *(const f32x4*)(ga + kt * 32 + 4);
        bf16x8 af;
#pragma unroll
        for (int e = 0; e < 4; e++) {
            af[e] = (__bf16)a0[e];
            af[e + 4] = (__bf16)a1[e];
        }
        const __bf16* gbk = gb + (size_t)kt * 3584;
#pragma unroll
        for (int n = 0; n < 7; n++) {
            bf16x8 bf = *(const bf16x8*)(gbk + n * 128);
            acc[n] = __builtin_amdgcn_mfma_f32_16x16x32_bf16(af, bf, acc[n], 0, 0, 0);
        }
    }

    float s0 = 0.f, s1 = 0.f, s2 = 0.f, s3 = 0.f;
#pragma unroll
    for (int n = 0; n < 7; n++) {
        int j = n * 16 + ln;
        if (j < AA1) {
            float bj = b1[j], wj = w2[j];
            s0 += tanhf(acc[n][0] + bj) * wj;
            s1 += tanhf(acc[n][1] + bj) * wj;
            s2 += tanhf(acc[n][2] + bj) * wj;
            s3 += tanhf(acc[n][3] + bj) * wj;
        }
    }
#pragma unroll
    for (int off = 1; off < 16; off <<= 1) {
        s0 += __shfl_xor(s0, off); s1 += __shfl_xor(s1, off);
        s2 += __shfl_xor(s2, off); s3 += __shfl_xor(s3, off);
    }
    if (ln == 0) {
        float bb = b2[0];
        int base = tok0 + w * 16 + q * 4;
        token_att[base + 0] = 1.f / (1.f + expf(-(s0 + bb)));
        token_att[base + 1] = 1.f / (1.f + expf(-(s1 + bb)));
        token_att[base + 2] = 1.f / (1.f + expf(-(s2 + bb)));
        token_att[base + 3] = 1.f / (1.f + expf(-(s3 + bb)));
    }
}

// ---------------------------------------------------------------------------
// Kernel 2 (fused mask+pool): grid (B, 12) x 256 threads.
// Every block recomputes the row's scan/segmax/mask/compaction locally
// (2 tokens per thread; row data is L2-hot, 12x redundancy ~free), builds
// cw/cs in LDS (no global round-trip), then pools its 64-h chunk.
// hc==0 additionally writes masked_out/stats, zeroes zsum[b] (+cnt2 at b==0).
// ---------------------------------------------------------------------------
__global__ __launch_bounds__(256) void k_poolmask(
        const float* __restrict__ hs, const float* __restrict__ token_att,
        const float* __restrict__ labels, const int* __restrict__ offm,
        float* __restrict__ masked_out, float* __restrict__ pooled,
        float4* __restrict__ stats_g, float* __restrict__ zsum,
        int* __restrict__ cnt2) {
    __shared__ int smax[SS];
    __shared__ float wl[SS];
    __shared__ short il[SS];
    __shared__ float red[256];
    __shared__ int wscan[4];
    __shared__ int wscan2[4];
    __shared__ float wred[5][4];
    __shared__ float sh_inv;
    __shared__ int sh_nnz;

    const int b = blockIdx.x, hc = blockIdx.y;
    const int t = threadIdx.x;
    const int lane = t & 63, wv = t >> 6;
    const int s0 = 2 * t, s1 = s0 + 1;

    // ---- word-start flags: offm int4 covers 2 tokens (fields .x / .z)
    const int4 om = ((const int4*)offm)[b * 256 + t];
    const int ns0 = (om.x == 0) ? 1 : 0;
    const int ns1 = (om.z == 0) ? 1 : 0;

    // ---- pair-inclusive scan of word-start flags
    int v = ns0 + ns1;
#pragma unroll
    for (int off = 1; off < 64; off <<= 1) {
        int o = __shfl_up(v, off);
        if (lane >= off) v += o;
    }
    if (lane == 63) wscan[wv] = v;
    smax[s0] = 0;
    smax[s1] = 0;
    __syncthreads();
    int woff = 0;
    for (int i = 0; i < 4; i++) woff += (i < wv) ? wscan[i] : 0;
    const int cum1 = v + woff;          // cumsum through s1
    const int cum0 = cum1 - ns1;        // cumsum through s0
    const int seg0 = max(cum0 - 1, 0);
    const int seg1 = max(cum1 - 1, 0);

    // ---- segment max (all tokens contribute; sigmoid>0 so int-order ok)
    const float2 ta = ((const float2*)token_att)[b * 256 + t];
    atomicMax(&smax[seg0], __float_as_int(ta.x));
    atomicMax(&smax[seg1], __float_as_int(ta.y));
    __syncthreads();

    const float2 lab = ((const float2*)labels)[b * 256 + t];
    const float wa0 = ns0 ? __int_as_float(smax[seg0]) : 0.f;
    const float wa1 = ns1 ? __int_as_float(smax[seg1]) : 0.f;
    const float m0 = (lab.x != -1.f && ns0) ? wa0 : 0.f;
    const float m1 = (lab.y != -1.f && ns1) ? wa1 : 0.f;
    if (hc == 0) {   // masked_out is at out+5: odd float offset -> scalar stores
        masked_out[b * SS + s0] = m0;
        masked_out[b * SS + s1] = m1;
    }
    const float zl0 = (lab.x != -1.f) ? lab.x : 0.f;
    const float zl1 = (lab.y != -1.f) ? lab.y : 0.f;
    const float tl0 = (m0 - zl0) * (m0 - zl0);
    const float tl1 = (m1 - zl1) * (m1 - zl1);
    const float on0 = (m0 == 0.f) ? 1.f : m0;
    const float on1 = (m1 == 0.f) ? 1.f : m1;

    float r0 = m0 + m1, r1 = tl0 + tl1;
    float r2 = fmaxf(m0, m1), r3 = fminf(on0, on1), r4 = fmaxf(lab.x, lab.y);
#pragma unroll
    for (int off = 32; off > 0; off >>= 1) {
        r0 += __shfl_xor(r0, off);
        r1 += __shfl_xor(r1, off);
        r2 = fmaxf(r2, __shfl_xor(r2, off));
        r3 = fminf(r3, __shfl_xor(r3, off));
        r4 = fmaxf(r4, __shfl_xor(r4, off));
    }
    if (lane == 0) {
        wred[0][wv] = r0; wred[1][wv] = r1; wred[2][wv] = r2;
        wred[3][wv] = r3; wred[4][wv] = r4;
    }

    // ---- compaction scan (pairs)
    const int nz0 = (m0 != 0.f) ? 1 : 0;
    const int nz1 = (m1 != 0.f) ? 1 : 0;
    int v2 = nz0 + nz1;
#pragma unroll
    for (int off = 1; off < 64; off <<= 1) {
        int o = __shfl_up(v2, off);
        if (lane >= off) v2 += o;
    }
    if (lane == 63) wscan2[wv] = v2;
    __syncthreads();
    int woff2 = 0;
    for (int i = 0; i < 4; i++) woff2 += (i < wv) ? wscan2[i] : 0;
    const int incl = v2 + woff2;        // nonzero count through s1
    if (nz1) { wl[incl - 1] = m1; il[incl - 1] = (short)s1; }
    if (nz0) { wl[incl - 1 - nz1] = m0; il[incl - 1 - nz1] = (short)s0; }

    if (t == 0) {
        float att = 0.f, tokl = 0.f, maxm = -1e30f, minone = 1e30f, slab = -1e30f;
        int nz = 0;
        for (int i = 0; i < 4; i++) {
            att += wred[0][i]; tokl += wred[1][i];
            maxm = fmaxf(maxm, wred[2][i]);
            minone = fminf(minone, wred[3][i]);
            slab = fmaxf(slab, wred[4][i]);
            nz += wscan2[i];
        }
        sh_inv = 1.f / att;
        sh_nnz = nz;
        if (hc == 0) {
            stats_g[b] = make_float4(tokl, maxm, minone, slab);
            zsum[b] = 0.f;
            if (b == 0) *cnt2 = 0;
        }
    }
    __syncthreads();

    // ---- pooling over compacted LDS list: 64 h x 4 K-slots
    const int nnz = sh_nnz;
    const float inv = sh_inv;
    const int h = (t & 63) + hc * 64;
    const int slot = t >> 6;
    const float* hsb = hs + (size_t)b * SS * HH + h;
    const int len = (nnz + 3) >> 2;
    const int i0 = slot * len;
    const int i1 = min(i0 + len, nnz);
    float a0 = 0.f, a1 = 0.f, a2 = 0.f, a3 = 0.f;
    int i = i0;
    for (; i + 4 <= i1; i += 4) {
        a0 += hsb[(size_t)il[i]     * HH] * wl[i];
        a1 += hsb[(size_t)il[i + 1] * HH] * wl[i + 1];
        a2 += hsb[(size_t)il[i + 2] * HH] * wl[i + 2];
        a3 += hsb[(size_t)il[i + 3] * HH] * wl[i + 3];
    }
    for (; i < i1; i++) a0 += hsb[(size_t)il[i] * HH] * wl[i];
    red[t] = (a0 + a1) + (a2 + a3);
    __syncthreads();
    if (t < 64)
        pooled[(size_t)b * HH + h] =
            (red[t] + red[t + 64] + red[t + 128] + red[t + 192]) * inv;
}

// ---------------------------------------------------------------------------
// Kernel 3 (fused sent+losses): grid (B, 5) x 256. Each block adds its
// partial of sum_c tanh(z_c)*sw2_c into zsum[b]; the LAST of the 320 blocks
// (device-scope fence + counter) computes sigmoid + all losses.
// ---------------------------------------------------------------------------
__global__ __launch_bounds__(256) void k_sentloss(
        const float* __restrict__ pooled, const float* __restrict__ sw1,
        const float* __restrict__ sb1, const float* __restrict__ sw2,
        const float* __restrict__ sb2, const float4* __restrict__ stats_g,
        float* __restrict__ zsum, int* __restrict__ cnt2,
        float* __restrict__ sent_out, float* __restrict__ out) {
    __shared__ float pl[HH];
    __shared__ float red[256];
    __shared__ int lastF;

    const int b = blockIdx.x, cc = blockIdx.y;
    const int tid = threadIdx.x;
    pl[tid]       = pooled[(size_t)b * HH + tid];
    pl[tid + 256] = pooled[(size_t)b * HH + tid + 256];
    pl[tid + 512] = pooled[(size_t)b * HH + tid + 512];
    __syncthreads();

    const int cl = tid & 63, kq = tid >> 6;
    const int c = cc * 60 + cl;
    float z = 0.f;
    if (cl < 60) {
        const int k0 = kq * 192;
        for (int k = k0; k < k0 + 192; k += 8) {
#pragma unroll
            for (int u = 0; u < 8; u++)
                z += pl[k + u] * sw1[(size_t)(k + u) * CC1 + c];
        }
    }
    red[tid] = z;
    __syncthreads();
    if (kq == 0) {
        float zz = red[tid] + red[tid + 64] + red[tid + 128] + red[tid + 192];
        float tt = 0.f;
        if (cl < 60) tt = tanhf(zz + sb1[c]) * sw2[c];
#pragma unroll
        for (int off = 32; off > 0; off >>= 1) tt += __shfl_xor(tt, off);
        if (cl == 0) atomicAdd(&zsum[b], tt);
    }
    __syncthreads();

    // ---- last-arriver does the final sigmoid + losses
    if (tid == 0) {
        __threadfence();                       // release our zsum add
        int old = atomicAdd(cnt2, 1);
        lastF = (old == BB * 5 - 1) ? 1 : 0;
    }
    __syncthreads();
    if (!lastF) return;
    __threadfence();                           // acquire all zsum adds

    if (tid < 64) {                            // wave 0: lane = batch row
        const float zs = atomicAdd(&zsum[tid], 0.f);   // coherent L2 read
        const float sv = 1.f / (1.f + expf(-(zs + sb2[0])));
        sent_out[tid] = sv;
        const float4 st = stats_g[tid];        // tokl, maxm, minone, slab
        float vs = sv - st.w; vs *= vs;
        float ra = st.z * st.z;
        float rb = st.y - st.w; rb *= rb;
        float s0 = vs, s1 = st.x, s2 = ra, s3 = rb;
#pragma unroll
        for (int off = 32; off > 0; off >>= 1) {
            s0 += __shfl_xor(s0, off);
            s1 += __shfl_xor(s1, off);
            s2 += __shfl_xor(s2, off);
            s3 += __shfl_xor(s3, off);
        }
        if (tid == 0) {
            out[1] = s0; out[2] = s1; out[3] = s2; out[4] = s3;
            out[0] = s0 + s1 + 0.01f * (s2 + s3);
        }
    }
}

extern "C" void kernel_launch(void* const* d_in, const int* in_sizes, int n_in,
                              void* d_out, int out_size, void* d_ws, size_t ws_size,
                              hipStream_t stream) {
    const float* hs  = (const float*)d_in[0];
    const float* w1  = (const float*)d_in[1];
    const float* b1  = (const float*)d_in[2];
    const float* w2  = (const float*)d_in[3];
    const float* b2  = (const float*)d_in[4];
    const float* sw1 = (const float*)d_in[5];
    const float* sb1 = (const float*)d_in[6];
    const float* sw2 = (const float*)d_in[7];
    const float* sb2 = (const float*)d_in[8];
    const float* labels = (const float*)d_in[9];
    const int*   offm   = (const int*)d_in[10];

    float* out = (float*)d_out;
    float* ws  = (float*)d_ws;

    // ws layout (float units), total 125249 floats (<= verified 125312):
    //   token_att : [0,      32768)
    //   w1i       : [32768,  75776)   (86016 bf16)
    //   pooled    : [75776, 124928)
    //   zsum      : [124928,124992)
    //   stats     : [124992,125248)   (64 float4, 16B-aligned)
    //   cnt2      : [125248,125249)
    float*  token_att = ws;
    __bf16* w1i    = (__bf16*)(ws + 32768);
    float*  pooled = ws + 75776;
    float*  zsum   = ws + 124928;
    float4* stats  = (float4*)(ws + 124992);
    int*    cnt2   = (int*)(ws + 125248);

    // d_out layout: [total, sentence_loss, token_loss, reg_a, reg_b,
    //                masked(64*512), sent(64)]
    float* masked_out = out + 5;
    float* sent_out   = out + 5 + BB * SS;

    hipLaunchKernelGGL(k_prep, dim3(336), dim3(256), 0, stream, w1, w1i);
    hipLaunchKernelGGL(k_token_att, dim3(512), dim3(256), 0, stream,
                       hs, w1i, b1, w2, b2, token_att);
    hipLaunchKernelGGL(k_poolmask, dim3(BB, 12), dim3(256), 0, stream,
                       hs, token_att, labels, offm, masked_out,
                       pooled, stats, zsum, cnt2);
    hipLaunchKernelGGL(k_sentloss, dim3(BB, 5), dim3(256), 0, stream,
                       pooled, sw1, sb1, sw2, sb2, stats, zsum, cnt2,
                       sent_out, out);
}

// Round 7
// 208.751 us; speedup vs baseline: 1.0049x; 1.0049x over previous
//
#include <hip/hip_runtime.h>
#include <math.h>

#define BB 64
#define SS 512
#define HH 768
#define AA1 100
#define CC1 300

typedef __bf16 bf16x8 __attribute__((ext_vector_type(8)));
typedef float f32x4 __attribute__((ext_vector_type(4)));

// ---------------------------------------------------------------------------
// Prep: (a) B image for token-att (chunk-major per 32-K tile, zero-pad j>=100)
//   w1i[((kt*4+q)*112 + j)*8 + e] = bf16(w1[(kt*32+q*8+e)*100 + j])
// (b) if doT: sw1T[c*768+k] = sw1[k*300+c]  (coalesced-read transpose)
// ---------------------------------------------------------------------------
__global__ __launch_bounds__(256) void k_prep(const float* __restrict__ w1,
                                              __bf16* __restrict__ w1i,
                                              const float* __restrict__ sw1,
                                              float* __restrict__ sw1T,
                                              int doT) {
    const int bb = blockIdx.x;
    if (bb < 336) {
        int idx = bb * 256 + threadIdx.x;   // 86016 = 336*256
        int j = idx % 112;
        int r = idx / 112;
        int e = r & 7, g = r >> 3;  // g = kt*4 + q
        int k = (g >> 2) * 32 + (g & 3) * 8 + e;
        float v = (j < AA1) ? w1[k * AA1 + j] : 0.f;
        w1i[((size_t)g * 112 + j) * 8 + e] = (__bf16)v;
    } else if (doT) {
        int idx = (bb - 336) * 256 + threadIdx.x;   // 230400 = 900*256
        int k = idx / CC1, c = idx - k * CC1;
        sw1T[(size_t)c * HH + k] = sw1[idx];        // read coalesced
    }
}

// ---------------------------------------------------------------------------
// Kernel 1: token attention, bf16 MFMA 16x16x32, barrier-free / LDS-free.
// Grid 512 x 256: wave w owns 16 tokens (1 M-tile) x 7 N-tiles.
// Lane (q,ln): A row = tok0+w*16+ln, k = q*8+e; B = w1[q*8+e][n*16+ln].
// ---------------------------------------------------------------------------
__global__ __launch_bounds__(256) void k_token_att(
        const float* __restrict__ hs, const __bf16* __restrict__ w1i,
        const float* __restrict__ b1, const float* __restrict__ w2,
        const float* __restrict__ b2, float* __restrict__ token_att) {
    const int tid = threadIdx.x;
    const int tok0 = blockIdx.x * 64;
    const int w = tid >> 6, lane = tid & 63;
    const int q = lane >> 4, ln = lane & 15;
    const int trow = tok0 + w * 16 + ln;

    f32x4 acc[7];
#pragma unroll
    for (int n = 0; n < 7; n++) acc[n] = (f32x4){0.f, 0.f, 0.f, 0.f};

    const float* ga = hs + (size_t)trow * HH + q * 8;
    const __bf16* gb = w1i + (size_t)(q * 112 + ln) * 8;

#pragma unroll 4
    for (int kt = 0; kt < 24; kt++) {
        f32x4 a0 = *(const f32x4*)(ga + kt * 32);
        f32x4 a1 = *(const f32x4*)(ga + kt * 32 + 4);
        bf16x8 af;
#pragma unroll
        for (int e = 0; e < 4; e++) {
            af[e] = (__bf16)a0[e];
            af[e + 4] = (__bf16)a1[e];
        }
        const __bf16* gbk = gb + (size_t)kt * 3584;
#pragma unroll
        for (int n = 0; n < 7; n++) {
            bf16x8 bf = *(const bf16x8*)(gbk + n * 128);
            acc[n] = __builtin_amdgcn_mfma_f32_16x16x32_bf16(af, bf, acc[n], 0, 0, 0);
        }
    }

    float s0 = 0.f, s1 = 0.f, s2 = 0.f, s3 = 0.f;
#pragma unroll
    for (int n = 0; n < 7; n++) {
        int j = n * 16 + ln;
        if (j < AA1) {
            float bj = b1[j], wj = w2[j];
            s0 += tanhf(acc[n][0] + bj) * wj;
            s1 += tanhf(acc[n][1] + bj) * wj;
            s2 += tanhf(acc[n][2] + bj) * wj;
            s3 += tanhf(acc[n][3] + bj) * wj;
        }
    }
#pragma unroll
    for (int off = 1; off < 16; off <<= 1) {
        s0 += __shfl_xor(s0, off); s1 += __shfl_xor(s1, off);
        s2 += __shfl_xor(s2, off); s3 += __shfl_xor(s3, off);
    }
    if (ln == 0) {
        float bb = b2[0];
        int base = tok0 + w * 16 + q * 4;
        token_att[base + 0] = 1.f / (1.f + expf(-(s0 + bb)));
        token_att[base + 1] = 1.f / (1.f + expf(-(s1 + bb)));
        token_att[base + 2] = 1.f / (1.f + expf(-(s2 + bb)));
        token_att[base + 3] = 1.f / (1.f + expf(-(s3 + bb)));
    }
}

// ---------------------------------------------------------------------------
// Kernel 2 (fused mask+pool): grid (B, 24) x 256 threads.
// Every block recomputes the row's scan/segmax/mask/compaction locally,
// builds cw/cs in LDS, then pools its 32-h chunk with 8 K-slots (deep ILP).
// hc==0 additionally writes masked_out/stats, zeroes zsum[b] (+cnt2 at b==0).
// ---------------------------------------------------------------------------
__global__ __launch_bounds__(256) void k_poolmask(
        const float* __restrict__ hs, const float* __restrict__ token_att,
        const float* __restrict__ labels, const int* __restrict__ offm,
        float* __restrict__ masked_out, float* __restrict__ pooled,
        float4* __restrict__ stats_g, float* __restrict__ zsum,
        int* __restrict__ cnt2) {
    __shared__ int smax[SS];
    __shared__ float wl[SS];
    __shared__ short il[SS];
    __shared__ float red[256];
    __shared__ int wscan[4];
    __shared__ int wscan2[4];
    __shared__ float wred[5][4];
    __shared__ float sh_inv;
    __shared__ int sh_nnz;

    const int b = blockIdx.x, hc = blockIdx.y;
    const int t = threadIdx.x;
    const int lane = t & 63, wv = t >> 6;
    const int s0 = 2 * t, s1 = s0 + 1;

    // ---- word-start flags: offm int4 covers 2 tokens (fields .x / .z)
    const int4 om = ((const int4*)offm)[b * 256 + t];
    const int ns0 = (om.x == 0) ? 1 : 0;
    const int ns1 = (om.z == 0) ? 1 : 0;

    // ---- pair-inclusive scan of word-start flags
    int v = ns0 + ns1;
#pragma unroll
    for (int off = 1; off < 64; off <<= 1) {
        int o = __shfl_up(v, off);
        if (lane >= off) v += o;
    }
    if (lane == 63) wscan[wv] = v;
    smax[s0] = 0;
    smax[s1] = 0;
    __syncthreads();
    int woff = 0;
    for (int i = 0; i < 4; i++) woff += (i < wv) ? wscan[i] : 0;
    const int cum1 = v + woff;          // cumsum through s1
    const int cum0 = cum1 - ns1;        // cumsum through s0
    const int seg0 = max(cum0 - 1, 0);
    const int seg1 = max(cum1 - 1, 0);

    // ---- segment max (all tokens contribute; sigmoid>0 so int-order ok)
    const float2 ta = ((const float2*)token_att)[b * 256 + t];
    atomicMax(&smax[seg0], __float_as_int(ta.x));
    atomicMax(&smax[seg1], __float_as_int(ta.y));
    __syncthreads();

    const float2 lab = ((const float2*)labels)[b * 256 + t];
    const float wa0 = ns0 ? __int_as_float(smax[seg0]) : 0.f;
    const float wa1 = ns1 ? __int_as_float(smax[seg1]) : 0.f;
    const float m0 = (lab.x != -1.f && ns0) ? wa0 : 0.f;
    const float m1 = (lab.y != -1.f && ns1) ? wa1 : 0.f;
    if (hc == 0) {
        masked_out[b * SS + s0] = m0;
        masked_out[b * SS + s1] = m1;
    }
    const float zl0 = (lab.x != -1.f) ? lab.x : 0.f;
    const float zl1 = (lab.y != -1.f) ? lab.y : 0.f;
    const float tl0 = (m0 - zl0) * (m0 - zl0);
    const float tl1 = (m1 - zl1) * (m1 - zl1);
    const float on0 = (m0 == 0.f) ? 1.f : m0;
    const float on1 = (m1 == 0.f) ? 1.f : m1;

    float r0 = m0 + m1, r1 = tl0 + tl1;
    float r2 = fmaxf(m0, m1), r3 = fminf(on0, on1), r4 = fmaxf(lab.x, lab.y);
#pragma unroll
    for (int off = 32; off > 0; off >>= 1) {
        r0 += __shfl_xor(r0, off);
        r1 += __shfl_xor(r1, off);
        r2 = fmaxf(r2, __shfl_xor(r2, off));
        r3 = fminf(r3, __shfl_xor(r3, off));
        r4 = fmaxf(r4, __shfl_xor(r4, off));
    }
    if (lane == 0) {
        wred[0][wv] = r0; wred[1][wv] = r1; wred[2][wv] = r2;
        wred[3][wv] = r3; wred[4][wv] = r4;
    }

    // ---- compaction scan (pairs)
    const int nz0 = (m0 != 0.f) ? 1 : 0;
    const int nz1 = (m1 != 0.f) ? 1 : 0;
    int v2 = nz0 + nz1;
#pragma unroll
    for (int off = 1; off < 64; off <<= 1) {
        int o = __shfl_up(v2, off);
        if (lane >= off) v2 += o;
    }
    if (lane == 63) wscan2[wv] = v2;
    __syncthreads();
    int woff2 = 0;
    for (int i = 0; i < 4; i++) woff2 += (i < wv) ? wscan2[i] : 0;
    const int incl = v2 + woff2;        // nonzero count through s1
    if (nz1) { wl[incl - 1] = m1; il[incl - 1] = (short)s1; }
    if (nz0) { wl[incl - 1 - nz1] = m0; il[incl - 1 - nz1] = (short)s0; }

    if (t == 0) {
        float att = 0.f, tokl = 0.f, maxm = -1e30f, minone = 1e30f, slab = -1e30f;
        int nz = 0;
        for (int i = 0; i < 4; i++) {
            att += wred[0][i]; tokl += wred[1][i];
            maxm = fmaxf(maxm, wred[2][i]);
            minone = fminf(minone, wred[3][i]);
            slab = fmaxf(slab, wred[4][i]);
            nz += wscan2[i];
        }
        sh_inv = 1.f / att;
        sh_nnz = nz;
        if (hc == 0) {
            stats_g[b] = make_float4(tokl, maxm, minone, slab);
            zsum[b] = 0.f;
            if (b == 0) *cnt2 = 0;
        }
    }
    __syncthreads();

    // ---- pooling over compacted LDS list: 32 h x 8 K-slots (deep ILP)
    const int nnz = sh_nnz;
    const float inv = sh_inv;
    const int h = (t & 31) + hc * 32;
    const int slot = t >> 5;            // 0..7
    const float* hsb = hs + (size_t)b * SS * HH + h;
    const int len = (nnz + 7) >> 3;
    const int i0 = slot * len;
    const int i1 = min(i0 + len, nnz);
    float a0 = 0.f, a1 = 0.f, a2 = 0.f, a3 = 0.f;
    int i = i0;
    for (; i + 4 <= i1; i += 4) {
        a0 += hsb[(size_t)il[i]     * HH] * wl[i];
        a1 += hsb[(size_t)il[i + 1] * HH] * wl[i + 1];
        a2 += hsb[(size_t)il[i + 2] * HH] * wl[i + 2];
        a3 += hsb[(size_t)il[i + 3] * HH] * wl[i + 3];
    }
    for (; i < i1; i++) a0 += hsb[(size_t)il[i] * HH] * wl[i];
    red[t] = (a0 + a1) + (a2 + a3);
    __syncthreads();
    if (t < 32) {
        float p = 0.f;
#pragma unroll
        for (int sl = 0; sl < 8; sl++) p += red[t + sl * 32];
        pooled[(size_t)b * HH + h] = p * inv;
    }
}

// ---------------------------------------------------------------------------
// Kernel 3 (fused sent+losses): grid (B, 5) x 256. Each block adds its
// partial of sum_c tanh(z_c)*sw2_c into zsum[b]; the LAST of the 320 blocks
// (device-scope fence + counter) computes sigmoid + all losses.
// useT: vectorized float4 loads from transposed sw1T (contiguous per column).
// ---------------------------------------------------------------------------
__global__ __launch_bounds__(256) void k_sentloss(
        const float* __restrict__ pooled, const float* __restrict__ sw1,
        const float* __restrict__ sw1T, const float* __restrict__ sb1,
        const float* __restrict__ sw2, const float* __restrict__ sb2,
        const float4* __restrict__ stats_g, float* __restrict__ zsum,
        int* __restrict__ cnt2, float* __restrict__ sent_out,
        float* __restrict__ out, int useT) {
    __shared__ __attribute__((aligned(16))) float pl[HH];
    __shared__ float red[256];
    __shared__ int lastF;

    const int b = blockIdx.x, cc = blockIdx.y;
    const int tid = threadIdx.x;
    pl[tid]       = pooled[(size_t)b * HH + tid];
    pl[tid + 256] = pooled[(size_t)b * HH + tid + 256];
    pl[tid + 512] = pooled[(size_t)b * HH + tid + 512];
    __syncthreads();

    const int cl = tid & 63, kq = tid >> 6;
    const int c = cc * 60 + cl;
    float z = 0.f;
    if (cl < 60) {
        if (useT) {
            const float4* wp = (const float4*)(sw1T + (size_t)c * HH + kq * 192);
            const float4* pp = (const float4*)(pl + kq * 192);
#pragma unroll 8
            for (int u = 0; u < 48; u++) {
                float4 a = pp[u], w4 = wp[u];
                z += a.x * w4.x + a.y * w4.y + a.z * w4.z + a.w * w4.w;
            }
        } else {
            const int k0 = kq * 192;
            for (int k = k0; k < k0 + 192; k += 8) {
#pragma unroll
                for (int u = 0; u < 8; u++)
                    z += pl[k + u] * sw1[(size_t)(k + u) * CC1 + c];
            }
        }
    }
    red[tid] = z;
    __syncthreads();
    if (kq == 0) {
        float zz = red[tid] + red[tid + 64] + red[tid + 128] + red[tid + 192];
        float tt = 0.f;
        if (cl < 60) tt = tanhf(zz + sb1[c]) * sw2[c];
#pragma unroll
        for (int off = 32; off > 0; off >>= 1) tt += __shfl_xor(tt, off);
        if (cl == 0) atomicAdd(&zsum[b], tt);
    }
    __syncthreads();

    // ---- last-arriver does the final sigmoid + losses
    if (tid == 0) {
        __threadfence();                       // release our zsum add
        int old = atomicAdd(cnt2, 1);
        lastF = (old == BB * 5 - 1) ? 1 : 0;
    }
    __syncthreads();
    if (!lastF) return;
    __threadfence();                           // acquire all zsum adds

    if (tid < 64) {                            // wave 0: lane = batch row
        const float zs = atomicAdd(&zsum[tid], 0.f);   // coherent L2 read
        const float sv = 1.f / (1.f + expf(-(zs + sb2[0])));
        sent_out[tid] = sv;
        const float4 st = stats_g[tid];        // tokl, maxm, minone, slab
        float vs = sv - st.w; vs *= vs;
        float ra = st.z * st.z;
        float rb = st.y - st.w; rb *= rb;
        float s0 = vs, s1 = st.x, s2 = ra, s3 = rb;
#pragma unroll
        for (int off = 32; off > 0; off >>= 1) {
            s0 += __shfl_xor(s0, off);
            s1 += __shfl_xor(s1, off);
            s2 += __shfl_xor(s2, off);
            s3 += __shfl_xor(s3, off);
        }
        if (tid == 0) {
            out[1] = s0; out[2] = s1; out[3] = s2; out[4] = s3;
            out[0] = s0 + s1 + 0.01f * (s2 + s3);
        }
    }
}

extern "C" void kernel_launch(void* const* d_in, const int* in_sizes, int n_in,
                              void* d_out, int out_size, void* d_ws, size_t ws_size,
                              hipStream_t stream) {
    const float* hs  = (const float*)d_in[0];
    const float* w1  = (const float*)d_in[1];
    const float* b1  = (const float*)d_in[2];
    const float* w2  = (const float*)d_in[3];
    const float* b2  = (const float*)d_in[4];
    const float* sw1 = (const float*)d_in[5];
    const float* sb1 = (const float*)d_in[6];
    const float* sw2 = (const float*)d_in[7];
    const float* sb2 = (const float*)d_in[8];
    const float* labels = (const float*)d_in[9];
    const int*   offm   = (const int*)d_in[10];

    float* out = (float*)d_out;
    float* ws  = (float*)d_ws;

    // ws layout (float units):
    //   token_att : [0,      32768)
    //   w1i       : [32768,  75776)   (86016 bf16)
    //   pooled    : [75776, 124928)
    //   zsum      : [124928,124992)
    //   stats     : [124992,125248)   (64 float4, 16B-aligned)
    //   cnt2      : [125248,125249)
    //   sw1T      : [131072, 361472)  (only if ws_size permits; gated)
    float*  token_att = ws;
    __bf16* w1i    = (__bf16*)(ws + 32768);
    float*  pooled = ws + 75776;
    float*  zsum   = ws + 124928;
    float4* stats  = (float4*)(ws + 124992);
    int*    cnt2   = (int*)(ws + 125248);
    float*  sw1T   = ws + 131072;

    const int doT = (ws_size >= (size_t)(131072 + 230400) * sizeof(float)) ? 1 : 0;

    // d_out layout: [total, sentence_loss, token_loss, reg_a, reg_b,
    //                masked(64*512), sent(64)]
    float* masked_out = out + 5;
    float* sent_out   = out + 5 + BB * SS;

    hipLaunchKernelGGL(k_prep, dim3(doT ? 1236 : 336), dim3(256), 0, stream,
                       w1, w1i, sw1, sw1T, doT);
    hipLaunchKernelGGL(k_token_att, dim3(512), dim3(256), 0, stream,
                       hs, w1i, b1, w2, b2, token_att);
    hipLaunchKernelGGL(k_poolmask, dim3(BB, 24), dim3(256), 0, stream,
                       hs, token_att, labels, offm, masked_out,
                       pooled, stats, zsum, cnt2);
    hipLaunchKernelGGL(k_sentloss, dim3(BB, 5), dim3(256), 0, stream,
                       pooled, sw1, sw1T, sb1, sw2, sb2, stats, zsum, cnt2,
                       sent_out, out, doT);
}